// Round 4
// baseline (629.445 us; speedup 1.0000x reference)
//
#include <hip/hip_runtime.h>
#include <math.h>

// ---------------------------------------------------------------------------
// LongRec.  B=256, S=200, D=U=128, NC=50000.
// alpha = softmax over singleton axis == 1.0 -> h_att = h_d; W_a is dead.
// Pipeline:
//   k0  : 128x128 weights fp32 -> bf16 k-swizzled for MFMA B-frags
//   k12 : MFMA precompute -> PRE fp32 (reg A-frag gather; fast sigmoid epilog;
//         decay = exp(-softplus(y)) == sigmoid(-y) algebraically).
//   k3  : 200-step recurrence.  R9: 1024 thr = 16 waves (4/SIMD, was 2) with
//         8-way k-split per column; reductions via DPP (quad_perm xor1/xor2 +
//         row_half_mirror xor7) on the VALU — no LDS-pipe shuffles; rolling
//         prefetch pointers, no per-step bounds branches.  2 lgkm barriers.
//   k0b : W_out -> bf16 WT[n][k]  (aliases PRE, dead after k3)
//   k4a : logits = h @ W_out + b_out via bf16 MFMA
//   k4b/c: row stats, softmax normalize
// ---------------------------------------------------------------------------

#define B_  256
#define S_  200
#define U_  128
#define NC  50000
#define NTOK (B_ * S_)       // 51200

// ws layout (in floats)
#define PRE_OFF   0
#define PRE_SZ    (NTOK * 768)            // 39321600 floats
#define LOG_OFF   PRE_SZ                  // logits: 12.8M floats
#define WSWZ_OFF  (PRE_SZ + 12800000)     // bf16 weights: 12*16384 ushort
#define HF_OFF    (PRE_SZ + 13107200)
#define RMAX_OFF  (HF_OFF + B_ * U_)
#define RSUM_OFF  (RMAX_OFF + B_)
// WT (bf16 W_out^T) aliases PRE_OFF — PRE dead after k3; k0b runs after k3.

// PRE per-token layout: [decay(0) | xr(128) | xz(256) | xh(384) | fdir(512) | psi(640)]

typedef float  float4v  __attribute__((ext_vector_type(4)));
typedef short  short8v  __attribute__((ext_vector_type(8)));

// fast transcendentals: v_exp_f32 (2^x) + v_rcp_f32, ~2-3 ULP, branchless.
__device__ __forceinline__ float fsig(float x) {      // 1/(1+e^-x)
    return __builtin_amdgcn_rcpf(1.f + __builtin_amdgcn_exp2f(-1.4426950408889634f * x));
}
__device__ __forceinline__ float ftanh(float x) {     // 1 - 2/(e^{2x}+1)
    return 1.f - 2.f * __builtin_amdgcn_rcpf(1.f + __builtin_amdgcn_exp2f(2.8853900817779268f * x));
}
__device__ __forceinline__ unsigned short f2bf(float f) {   // RNE
    unsigned int u = __float_as_uint(f);
    u = (u + 0x7fffu + ((u >> 16) & 1u)) >> 16;
    return (unsigned short)u;
}
__device__ __forceinline__ unsigned int pack2bf(float a, float b) {
    return (unsigned int)f2bf(a) | ((unsigned int)f2bf(b) << 16);
}
// Barrier draining only LDS (lgkmcnt) — global prefetches stay in flight.
__device__ __forceinline__ void bar_lds() {
    asm volatile("s_waitcnt lgkmcnt(0)\n\ts_barrier" ::: "memory");
}
// VALU cross-lane add via DPP.  0xB1 = quad_perm xor1, 0x4E = quad_perm xor2,
// 0x141 = row_half_mirror (lane ^ 7 within 8-lane groups).
template<int CTRL>
__device__ __forceinline__ float dppadd(float x) {
    return x + __int_as_float(
        __builtin_amdgcn_mov_dpp(__float_as_int(x), CTRL, 0xF, 0xF, true));
}

// ---------------------------------------------------------------------------
// k0: 12 x [128][128] fp32 -> bf16 swizzled  dst[((k>>5)*128 + n)*32 + (k&31)]
__global__ __launch_bounds__(256) void k0_wconv(
    const float* s0, const float* s1, const float* s2, const float* s3,
    const float* s4, const float* s5, const float* s6, const float* s7,
    const float* s8, const float* s9, const float* s10, const float* s11,
    unsigned short* __restrict__ dst)
{
    const float* srcs[12] = { s0,s1,s2,s3,s4,s5,s6,s7,s8,s9,s10,s11 };
    const float* S = srcs[blockIdx.x];
    unsigned short* D = dst + (size_t)blockIdx.x * 16384;
    for (int i = threadIdx.x; i < 16384; i += 256) {
        int k5 = i & 31, n = (i >> 5) & 127, kb = i >> 12;
        D[i] = f2bf(S[(size_t)(kb * 32 + k5) * 128 + n]);
    }
}

// ---------------------------------------------------------------------------
// k0b: W_out [128][50000] fp32 -> WT [n][k] bf16
__global__ __launch_bounds__(256) void k0b_woutT(const float* __restrict__ W_out,
                                                 unsigned short* __restrict__ WT)
{
    int n  = blockIdx.x * 64 + (threadIdx.x >> 2);
    int k0 = (threadIdx.x & 3) * 32;
    if (n >= NC) return;
#pragma unroll 8
    for (int i = 0; i < 32; ++i)
        WT[(size_t)n * 128 + k0 + i] = f2bf(W_out[(size_t)(k0 + i) * NC + n]);
}

// ---------------------------------------------------------------------------
// MFMA helpers (16x16x32 bf16).  A-frag: lane holds A[m0+(lane&15)][kb*32+quad*8+j].
// B-frag (swizzled W): lane holds W[kb*32+quad*8+j][nt*16+(lane&15)].
// C/D: col = lane&15, row = quad*4 + reg.
__device__ __forceinline__ void gemm_k128(const unsigned short (*A)[136],
                                          int m0, int l16, int quad,
                                          const unsigned short* __restrict__ Wm,
                                          float4v acc[8]) {
#pragma unroll
    for (int kb = 0; kb < 4; ++kb) {
        short8v av = *(const short8v*)&A[m0 + l16][kb * 32 + quad * 8];
#pragma unroll
        for (int nt = 0; nt < 8; ++nt) {
            short8v bv = *(const short8v*)(Wm + (((kb * 128) + nt * 16 + l16) * 32 + quad * 8));
            acc[nt] = __builtin_amdgcn_mfma_f32_16x16x32_bf16(av, bv, acc[nt], 0, 0, 0);
        }
    }
}
// A-frags held in registers (gathered directly from the embedding tables).
__device__ __forceinline__ void gemm_reg(const short8v a[4], int l16, int quad,
                                         const unsigned short* __restrict__ Wm,
                                         float4v acc[8]) {
#pragma unroll
    for (int kb = 0; kb < 4; ++kb) {
#pragma unroll
        for (int nt = 0; nt < 8; ++nt) {
            short8v bv = *(const short8v*)(Wm + (((kb * 128) + nt * 16 + l16) * 32 + quad * 8));
            acc[nt] = __builtin_amdgcn_mfma_f32_16x16x32_bf16(a[kb], bv, acc[nt], 0, 0, 0);
        }
    }
}
__device__ __forceinline__ void zero8(float4v acc[8]) {
#pragma unroll
    for (int i = 0; i < 8; ++i) acc[i] = (float4v)0.0f;
}
// 8 contiguous f32 -> one bf16 A-frag word (16B)
__device__ __forceinline__ short8v cvt8(const float* __restrict__ p) {
    float4 v0 = *(const float4*)p;
    float4 v1 = *(const float4*)(p + 4);
    union { unsigned int u[4]; short8v s; } r;
    r.u[0] = pack2bf(v0.x, v0.y);
    r.u[1] = pack2bf(v0.z, v0.w);
    r.u[2] = pack2bf(v1.x, v1.y);
    r.u[3] = pack2bf(v1.z, v1.w);
    return r.s;
}

// ---------------------------------------------------------------------------
// k12: fused MFMA precompute.  grid = NTOK/64, block = 256 (4 waves),
// wave w owns tokens t0+16w .. t0+16w+15.  No barriers (all LDS is wave-local).
__global__ __launch_bounds__(256, 4) void k12_precompute(
    const int* __restrict__ item, const int* __restrict__ tix, const int* __restrict__ frq,
    const float* __restrict__ Ei, const float* __restrict__ Et, const float* __restrict__ Ef,
    const float* __restrict__ b_r, const float* __restrict__ b_z, const float* __restrict__ b_h,
    const float* __restrict__ b_tg, const float* __restrict__ b_fg,
    const float* __restrict__ b_delta, const float* __restrict__ b_f_dir, const float* __restrict__ b_psi,
    const unsigned short* __restrict__ WZ,
    float* __restrict__ PRE)
{
    __shared__ unsigned short Atg[64][136];   // tg (bf16, A-layout)
    __shared__ unsigned short Afg[64][136];   // fg (bf16, A-layout)

    const int t0   = blockIdx.x * 64;
    const int tid  = threadIdx.x;
    const int lane = tid & 63;
    const int wid  = tid >> 6;
    const int quad = lane >> 4;
    const int l16  = lane & 15;
    const int m0   = wid * 16;

    // --- gather embedding rows straight into register A-frags ---
    const int tok = t0 + m0 + l16;
    const int it  = item[tok], tt = tix[tok], ft = frq[tok];
    const float* pei = Ei + (size_t)it * U_ + quad * 8;
    const float* pet = Et + (size_t)tt * U_ + quad * 8;
    const float* pef = Ef + (size_t)ft * U_ + quad * 8;

    short8v axi[4], axt[4], axf[4];
#pragma unroll
    for (int kb = 0; kb < 4; ++kb) axi[kb] = cvt8(pei + kb * 32);
#pragma unroll
    for (int kb = 0; kb < 4; ++kb) axt[kb] = cvt8(pet + kb * 32);
#pragma unroll
    for (int kb = 0; kb < 4; ++kb) axf[kb] = cvt8(pef + kb * 32);

    const unsigned short* WM0  = WZ;                 // W_xtg
    const unsigned short* WM1  = WZ + 1  * 16384;    // W_tg
    const unsigned short* WM2  = WZ + 2  * 16384;    // W_xfg
    const unsigned short* WM3  = WZ + 3  * 16384;    // W_fg
    const unsigned short* WM4  = WZ + 4  * 16384;    // W_xr
    const unsigned short* WM5  = WZ + 5  * 16384;    // W_xz
    const unsigned short* WM6  = WZ + 6  * 16384;    // W_xh
    const unsigned short* WM7  = WZ + 7  * 16384;    // W_delta top (tg rows)
    const unsigned short* WM8  = WZ + 8  * 16384;    // W_delta bot (fg rows)
    const unsigned short* WM9  = WZ + 9  * 16384;    // W_f_dir
    const unsigned short* WM10 = WZ + 10 * 16384;    // W_psi

    float4v acc[8];
    const int tokbase = t0 + m0 + quad * 4;

    // ---- tg = sigmoid(xi@W_xtg + xt@W_tg + b_tg) -> Atg (bf16, A-layout) ----
    zero8(acc);
    gemm_reg(axi, l16, quad, WM0, acc);
    gemm_reg(axt, l16, quad, WM1, acc);
#pragma unroll
    for (int nt = 0; nt < 8; ++nt) {
        int n = nt * 16 + l16;
        float bb = b_tg[n];
#pragma unroll
        for (int r = 0; r < 4; ++r)
            Atg[m0 + quad * 4 + r][n] = f2bf(fsig(acc[nt][r] + bb));
    }
    // ---- fg = sigmoid(xi@W_xfg + xf@W_fg + b_fg) -> Afg ----
    zero8(acc);
    gemm_reg(axi, l16, quad, WM2, acc);
    gemm_reg(axf, l16, quad, WM3, acc);
#pragma unroll
    for (int nt = 0; nt < 8; ++nt) {
        int n = nt * 16 + l16;
        float bb = b_fg[n];
#pragma unroll
        for (int r = 0; r < 4; ++r)
            Afg[m0 + quad * 4 + r][n] = f2bf(fsig(acc[nt][r] + bb));
    }

    // ---- xr, xz, xh (xi only — hides the Atg/Afg LDS write->read latency) ----
    {
        const unsigned short* Wx[3] = { WM4, WM5, WM6 };
        const float* bx[3] = { b_r, b_z, b_h };
        const int    off[3] = { 128, 256, 384 };
#pragma unroll
        for (int m = 0; m < 3; ++m) {
            zero8(acc);
            gemm_reg(axi, l16, quad, Wx[m], acc);
#pragma unroll
            for (int nt = 0; nt < 8; ++nt) {
                int n = nt * 16 + l16;
                float bb = bx[m][n];
#pragma unroll
                for (int r = 0; r < 4; ++r)
                    PRE[(size_t)(tokbase + r) * 768 + off[m] + n] = acc[nt][r] + bb;
            }
        }
    }
    // ---- decay = exp(-softplus(y)) == sigmoid(-y), y = [tg|fg]@W_delta + b ----
    zero8(acc);
    gemm_k128(Atg, m0, l16, quad, WM7, acc);
    gemm_k128(Afg, m0, l16, quad, WM8, acc);
#pragma unroll
    for (int nt = 0; nt < 8; ++nt) {
        int n = nt * 16 + l16;
        float bb = b_delta[n];
#pragma unroll
        for (int r = 0; r < 4; ++r)
            PRE[(size_t)(tokbase + r) * 768 + 0 + n] = fsig(-(acc[nt][r] + bb));
    }
    // ---- fdir = fg@W_f_dir + b ----
    zero8(acc);
    gemm_k128(Afg, m0, l16, quad, WM9, acc);
#pragma unroll
    for (int nt = 0; nt < 8; ++nt) {
        int n = nt * 16 + l16;
        float bb = b_f_dir[n];
#pragma unroll
        for (int r = 0; r < 4; ++r)
            PRE[(size_t)(tokbase + r) * 768 + 512 + n] = acc[nt][r] + bb;
    }
    // ---- psi = sigmoid(fg@W_psi + b) ----
    zero8(acc);
    gemm_k128(Afg, m0, l16, quad, WM10, acc);
#pragma unroll
    for (int nt = 0; nt < 8; ++nt) {
        int n = nt * 16 + l16;
        float bb = b_psi[n];
#pragma unroll
        for (int r = 0; r < 4; ++r)
            PRE[(size_t)(tokbase + r) * 768 + 640 + n] = fsig(acc[nt][r] + bb);
    }
}

// ---------------------------------------------------------------------------
// k3: one workgroup per batch row; 1024 threads = 16 waves (4/SIMD).
//   8-way k-split per output column: kg = lane&7 owns k in {32q + 4kg + j},
//   q<4, j<4 (16 k) — interleaved so the octet's float4 reads hit 8 distinct
//   bank spans.  Reduction = DPP butterfly xor1/xor2/xor7 (pure VALU).
//   P1: waves 0-7 r-matvec, 8-15 z-matvec; octet owns 2 cols (colA).
//   P2: all 16 waves h-matvec; octet owns 1 col (colB); update in-register.
//   2 lgkm-only barriers/step; rolling prefetch pointers (over-reads past the
//   row end land in the allocated LOG region and are never consumed).
__global__ __launch_bounds__(1024, 4) void k3_scan(
    const float* __restrict__ PRE,
    const float* __restrict__ W_hr, const float* __restrict__ W_hz, const float* __restrict__ W_hh,
    unsigned short* __restrict__ Hb)
{
    const int b    = blockIdx.x;
    const int tid  = threadIdx.x;
    const int lane = tid & 63;
    const int wid  = tid >> 6;          // 0..15
    const int oct  = lane >> 3;         // 0..7
    const int kg   = lane & 7;          // 0..7 (k-group)

    const int colA = ((wid & 7) << 4) + (oct << 1);   // P1: 2 cols
    const int colB = (wid << 3) + oct;                // P2: 1 col

    // --- loop-invariant weights pinned in VGPRs ---
    const float* Wrz = (wid < 8) ? W_hr : W_hz;
    float wrz[32];   // [(q*4+j)*2+c] = Wrz[32q+4kg+j][colA+c]
#pragma unroll
    for (int q = 0; q < 4; ++q)
#pragma unroll
        for (int j = 0; j < 4; ++j) {
            float2 wv = *(const float2*)&Wrz[(size_t)(32 * q + 4 * kg + j) * U_ + colA];
            wrz[(q * 4 + j) * 2 + 0] = wv.x;
            wrz[(q * 4 + j) * 2 + 1] = wv.y;
        }
    float whh[16];   // [q*4+j] = W_hh[32q+4kg+j][colB]
#pragma unroll
    for (int q = 0; q < 4; ++q)
#pragma unroll
        for (int j = 0; j < 4; ++j)
            whh[q * 4 + j] = W_hh[(size_t)(32 * q + 4 * kg + j) * U_ + colB];
#pragma unroll
    for (int k = 0; k < 32; ++k) asm volatile("" : "+v"(wrz[k]));
#pragma unroll
    for (int k = 0; k < 16; ++k) asm volatile("" : "+v"(whh[k]));

    __shared__ __align__(16) float hd[U_];
    __shared__ __align__(16) float rh[U_];
    __shared__ __align__(16) float zb[U_];
    if (tid < U_) hd[tid] = 0.f;    // h0 = 0 -> h_d(step 0) = 0

    const float* pre = PRE + (size_t)b * S_ * 768;
    // rolling prefetch pointers (point at step s+1 inside the loop)
    const float* pA = pre + ((wid < 8) ? 128 : 256) + colA;  // xr | xz (float2)
    const float* pX = pre + 384 + colB;   // xh; fdir = pX+128; psi = pX+256
    const float* pD = pre + 768 + colB;   // decay[s+1]

    float c_p0, c_p1, c_xh, c_fd, c_ps, c_dk;
    {
        float2 t = *(const float2*)pA;
        c_p0 = t.x; c_p1 = t.y;
        c_xh = pX[0]; c_fd = pX[128]; c_ps = pX[256]; c_dk = pD[0];
    }
    bar_lds();

    float hn = 0.f;
    for (int s = 0; s < S_; ++s) {
        // prefetch step s+1 constants (stay in vmcnt flight across barriers)
        pA += 768; pX += 768; pD += 768;
        float2 tn = *(const float2*)pA;
        float n_xh = pX[0], n_fd = pX[128], n_ps = pX[256], n_dk = pD[0];

        // ---- P1: r/z matvec over hd + DPP reduce + sigmoid ----
        float2 hdA = *(const float2*)&hd[colA];   // for rh = sig(r)*hd
        float a0 = 0.f, a1 = 0.f, b0 = 0.f, b1 = 0.f;
#pragma unroll
        for (int q = 0; q < 4; ++q) {
            float4 hv = *(const float4*)&hd[32 * q + 4 * kg];
            float& s0 = (q & 1) ? b0 : a0;
            float& s1 = (q & 1) ? b1 : a1;
            s0 = fmaf(hv.x, wrz[(q * 4 + 0) * 2 + 0], s0); s1 = fmaf(hv.x, wrz[(q * 4 + 0) * 2 + 1], s1);
            s0 = fmaf(hv.y, wrz[(q * 4 + 1) * 2 + 0], s0); s1 = fmaf(hv.y, wrz[(q * 4 + 1) * 2 + 1], s1);
            s0 = fmaf(hv.z, wrz[(q * 4 + 2) * 2 + 0], s0); s1 = fmaf(hv.z, wrz[(q * 4 + 2) * 2 + 1], s1);
            s0 = fmaf(hv.w, wrz[(q * 4 + 3) * 2 + 0], s0); s1 = fmaf(hv.w, wrz[(q * 4 + 3) * 2 + 1], s1);
        }
        a0 += b0; a1 += b1;
        a0 = dppadd<0xB1>(a0); a0 = dppadd<0x4E>(a0); a0 = dppadd<0x141>(a0);
        a1 = dppadd<0xB1>(a1); a1 = dppadd<0x4E>(a1); a1 = dppadd<0x141>(a1);
        if (kg == 0) {
            float s0 = fsig(c_p0 + a0), s1 = fsig(c_p1 + a1);
            if (wid < 8) *(float2*)&rh[colA] = make_float2(s0 * hdA.x, s1 * hdA.y);
            else         *(float2*)&zb[colA] = make_float2(s0, s1);
        }
        bar_lds();   // rh, zb ready

        // ---- P2: h matvec over rh (all 16 waves) + update ----
        float z_  = zb[colB];
        float hd_ = hd[colB];
        float a2 = 0.f, b2 = 0.f;
#pragma unroll
        for (int q = 0; q < 4; ++q) {
            float4 rv = *(const float4*)&rh[32 * q + 4 * kg];
            float& s2 = (q & 1) ? b2 : a2;
            s2 = fmaf(rv.x, whh[q * 4 + 0], s2);
            s2 = fmaf(rv.y, whh[q * 4 + 1], s2);
            s2 = fmaf(rv.z, whh[q * 4 + 2], s2);
            s2 = fmaf(rv.w, whh[q * 4 + 3], s2);
        }
        a2 += b2;
        a2 = dppadd<0xB1>(a2); a2 = dppadd<0x4E>(a2); a2 = dppadd<0x141>(a2);
        float hb = ftanh(c_xh + a2);
        float hf = ftanh(hb + c_fd);
        float hc = (1.f - c_ps) * hb + c_ps * hf;
        hn = (1.f - z_) * hd_ + z_ * hc;          // alpha==1 -> h_att = h_d
        if (kg == 0) hd[colB] = c_dk * hn;        // decay[s+1] * h_new
        bar_lds();   // hd ready for next step

        c_p0 = tn.x; c_p1 = tn.y; c_xh = n_xh; c_fd = n_fd; c_ps = n_ps; c_dk = n_dk;
    }
    if (kg == 0) Hb[(size_t)b * U_ + colB] = f2bf(hn);
}

// ---------------------------------------------------------------------------
// k4a: logits = h @ W_out + b_out via bf16 MFMA.
__global__ __launch_bounds__(256) void k4a_logits(
    const unsigned short* __restrict__ Hb, const unsigned short* __restrict__ WT,
    const float* __restrict__ b_out, float* __restrict__ logits)
{
    const int tid  = threadIdx.x;
    const int lane = tid & 63, wid = tid >> 6;
    const int quad = lane >> 4, l16 = lane & 15;
    const int rb = blockIdx.y * 64 + wid * 16;
    const int cb = blockIdx.x * 128;

    short8v av[4];
#pragma unroll
    for (int kb = 0; kb < 4; ++kb)
        av[kb] = *(const short8v*)&Hb[(size_t)(rb + l16) * 128 + kb * 32 + quad * 8];

    float4v acc[8];
#pragma unroll
    for (int i = 0; i < 8; ++i) acc[i] = (float4v)0.0f;

#pragma unroll
    for (int kb = 0; kb < 4; ++kb) {
#pragma unroll
        for (int nt = 0; nt < 8; ++nt) {
            short8v bv = *(const short8v*)&WT[(size_t)(cb + nt * 16 + l16) * 128 + kb * 32 + quad * 8];
            acc[nt] = __builtin_amdgcn_mfma_f32_16x16x32_bf16(av[kb], bv, acc[nt], 0, 0, 0);
        }
    }
#pragma unroll
    for (int nt = 0; nt < 8; ++nt) {
        int n = cb + nt * 16 + l16;
        if (n < NC) {
            float bb = b_out[n];
#pragma unroll
            for (int r = 0; r < 4; ++r)
                logits[(size_t)(rb + quad * 4 + r) * NC + n] = acc[nt][r] + bb;
        }
    }
}

// ---------------------------------------------------------------------------
__global__ __launch_bounds__(256) void k4b_rowstats(
    const float* __restrict__ logits, float* __restrict__ rmax, float* __restrict__ rsum)
{
    const int r = blockIdx.x;
    const int tid = threadIdx.x;
    const float* row = logits + (size_t)r * NC;

    float m = -INFINITY, s = 0.f;
    for (int c = tid; c < NC; c += 256) {
        float x = row[c];
        float mn = fmaxf(m, x);
        s = s * expf(m - mn) + expf(x - mn);
        m = mn;
    }
    __shared__ float sm[256], ss[256];
    sm[tid] = m; ss[tid] = s;
    __syncthreads();
    for (int off = 128; off > 0; off >>= 1) {
        if (tid < off) {
            float m2 = sm[tid + off], s2 = ss[tid + off];
            float M = fmaxf(sm[tid], m2);
            ss[tid] = ss[tid] * expf(sm[tid] - M) + s2 * expf(m2 - M);
            sm[tid] = M;
        }
        __syncthreads();
    }
    if (tid == 0) { rmax[r] = sm[0]; rsum[r] = ss[0]; }
}

__global__ __launch_bounds__(256) void k4c_norm(
    const float* __restrict__ logits, const float* __restrict__ rmax,
    const float* __restrict__ rsum, float* __restrict__ out)
{
    const int r = blockIdx.y;
    const int c = blockIdx.x * 256 + threadIdx.x;
    if (c < NC) {
        size_t i = (size_t)r * NC + c;
        out[i] = expf(logits[i] - rmax[r]) / rsum[r];
    }
}

// ---------------------------------------------------------------------------
extern "C" void kernel_launch(void* const* d_in, const int* in_sizes, int n_in,
                              void* d_out, int out_size, void* d_ws, size_t ws_size,
                              hipStream_t stream) {
    const int*   item   = (const int*)d_in[0];
    const int*   tix    = (const int*)d_in[1];
    const int*   frq    = (const int*)d_in[2];
    const float* Ei     = (const float*)d_in[3];
    const float* Et     = (const float*)d_in[4];
    const float* Ef     = (const float*)d_in[5];
    const float* W_xr   = (const float*)d_in[6];
    const float* W_hr   = (const float*)d_in[7];
    const float* b_r    = (const float*)d_in[8];
    const float* W_xz   = (const float*)d_in[9];
    const float* W_hz   = (const float*)d_in[10];
    const float* b_z    = (const float*)d_in[11];
    const float* W_xh   = (const float*)d_in[12];
    const float* W_hh   = (const float*)d_in[13];
    const float* b_h    = (const float*)d_in[14];
    const float* W_xtg  = (const float*)d_in[15];
    const float* W_tg   = (const float*)d_in[16];
    const float* b_tg   = (const float*)d_in[17];
    const float* W_xfg  = (const float*)d_in[18];
    const float* W_fg   = (const float*)d_in[19];
    const float* b_fg   = (const float*)d_in[20];
    const float* W_delta= (const float*)d_in[21];
    const float* b_delta= (const float*)d_in[22];
    const float* W_f_dir= (const float*)d_in[23];
    const float* b_f_dir= (const float*)d_in[24];
    const float* W_psi  = (const float*)d_in[25];
    const float* b_psi  = (const float*)d_in[26];
    // d_in[27] = W_a — dead (softmax over singleton axis == 1)
    const float* W_out  = (const float*)d_in[28];
    const float* b_out  = (const float*)d_in[29];
    float* out = (float*)d_out;

    float* ws   = (float*)d_ws;
    float* PRE  = ws + PRE_OFF;
    float* LOG  = ws + LOG_OFF;
    unsigned short* WSWZ = (unsigned short*)(ws + WSWZ_OFF);
    unsigned short* WT   = (unsigned short*)(ws + PRE_OFF);   // aliases PRE (dead after k3)
    unsigned short* Hb   = (unsigned short*)(ws + HF_OFF);
    float* RMAX = ws + RMAX_OFF;
    float* RSUM = ws + RSUM_OFF;

    k0_wconv<<<12, 256, 0, stream>>>(
        W_xtg, W_tg, W_xfg, W_fg, W_xr, W_xz, W_xh,
        W_delta, W_delta + 128 * 128, W_f_dir, W_psi,
        W_psi /* pad slot 11, unused by k12 */, WSWZ);
    k12_precompute<<<NTOK / 64, 256, 0, stream>>>(
        item, tix, frq, Ei, Et, Ef,
        b_r, b_z, b_h, b_tg, b_fg, b_delta, b_f_dir, b_psi,
        WSWZ, PRE);
    k3_scan<<<B_, 1024, 0, stream>>>(PRE, W_hr, W_hz, W_hh, Hb);
    k0b_woutT<<<(NC + 63) / 64, 256, 0, stream>>>(W_out, WT);
    k4a_logits<<<dim3((NC + 127) / 128, B_ / 64), 256, 0, stream>>>(Hb, WT, b_out, LOG);
    k4b_rowstats<<<B_, 256, 0, stream>>>(LOG, RMAX, RSUM);
    k4c_norm<<<dim3((NC + 255) / 256, B_), 256, 0, stream>>>(LOG, RMAX, RSUM, out);
}